// Round 3
// baseline (526.300 us; speedup 1.0000x reference)
//
#include <hip/hip_runtime.h>
#include <math.h>

// CEpsilonLoss: out = -mean(V) + mean_i( log( mean_j exp((V[j] - c[i,j]) * eps) ) ) / eps
// c[i,j] = sum_d |A[i,d] - B[j,d]|  (FP32 VALU-bound: |a-b| is not bilinear -> no MFMA).
//
// v3: staging via global_load_lds (width=16, async DMA, no VGPR roundtrip, no
// ds_writes -> no write bank conflicts), i-major LDS rows of BK=32 floats with
// float4-chunk XOR swizzle for conflict-free ds_read_b128 fragments. The
// swizzle is produced by PRE-SWIZZLING the per-lane global source address
// (linear LDS dest + inverse-swizzled source + swizzled read). Double-buffered
// 2-phase k-loop: issue next tile's loads before computing current tile.

#define D_DIM 1024
#define BI 128   // rows (real) per block
#define BJ 64    // cols (fake) per block
#define BK 32    // k-tile
#define TI 8     // per-thread rows
#define TJ 4     // per-thread cols

typedef __attribute__((address_space(3))) void lds_void_t;
typedef const __attribute__((address_space(1))) void glb_void_t;

__device__ __forceinline__ void gload16(const float* g, float* l) {
    __builtin_amdgcn_global_load_lds((glb_void_t*)g, (lds_void_t*)l, 16, 0, 0);
}

__global__ __launch_bounds__(256, 2)
void ceps_cdist_partial(const float* __restrict__ A,
                        const float* __restrict__ B,
                        const float* __restrict__ V,
                        float* __restrict__ pmax,   // [N][M/BJ]
                        float* __restrict__ psums,  // [N][M/BJ]
                        int N, int M)
{
    // i-major: row i = 32 floats (8 float4 chunks), chunk p stores logical
    // chunk p ^ key(i).  key_A(i) = (i>>3)&3, key_B(j) = (j>>2)&7.
    __shared__ float As[2][BI * BK];   // 2 x 16 KB
    __shared__ float Bs[2][BJ * BK];   // 2 x  8 KB

    const int t    = threadIdx.x;
    const int tx   = t & 15;          // j group: rows tx*4..tx*4+3 of B tile
    const int ty   = t >> 4;          // i group: rows ty*8..ty*8+7 of A tile
    const int w    = t >> 6;          // wave id 0..3
    const int l    = t & 63;
    const int lrow = l >> 3;          // 0..7  (row within 8-row store block)
    const int lchk = l & 7;           // 0..7  (float4 chunk within row)

    const int jb = blockIdx.x;
    const int ib = blockIdx.y;
    const int i0 = ib * BI;
    const int j0 = jb * BJ;
    const int MB = M / BJ;

    // Per-lane pre-swizzled global source pointers.
    // A store-instr q (q=0..3) covers rows i0 + w*32 + q*8 + lrow; its key is
    // ((w*4+q)&3) = q, so lane lchk must fetch global chunk (lchk ^ q).
    const float* pa0 = A + (size_t)(i0 + w * 32 + 0 + lrow) * D_DIM + 4 * (lchk ^ 0);
    const float* pa1 = A + (size_t)(i0 + w * 32 + 8 + lrow) * D_DIM + 4 * (lchk ^ 1);
    const float* pa2 = A + (size_t)(i0 + w * 32 + 16 + lrow) * D_DIM + 4 * (lchk ^ 2);
    const float* pa3 = A + (size_t)(i0 + w * 32 + 24 + lrow) * D_DIM + 4 * (lchk ^ 3);
    // B store-instr p (p=0..1) covers rows j0 + w*16 + p*8 + lrow; per-lane
    // key = ((j>>2)&7) = (w*4 + p*2 + (lrow>>2)) & 7.
    const int kb0 = (w * 4 + 0 + (lrow >> 2)) & 7;
    const int kb1 = (w * 4 + 2 + (lrow >> 2)) & 7;
    const float* pb0 = B + (size_t)(j0 + w * 16 + 0 + lrow) * D_DIM + 4 * (lchk ^ kb0);
    const float* pb1 = B + (size_t)(j0 + w * 16 + 8 + lrow) * D_DIM + 4 * (lchk ^ kb1);

    float acc[TI][TJ];
    #pragma unroll
    for (int r = 0; r < TI; ++r)
        #pragma unroll
        for (int s = 0; s < TJ; ++s) acc[r][s] = 0.0f;

    const int kA = ty & 3;
    const int kB = tx & 7;

    auto stage = [&](int buf) {
        float* Ad = &As[buf][(w * 32) * BK];
        gload16(pa0, Ad + 0 * 8 * BK);
        gload16(pa1, Ad + 1 * 8 * BK);
        gload16(pa2, Ad + 2 * 8 * BK);
        gload16(pa3, Ad + 3 * 8 * BK);
        float* Bd = &Bs[buf][(w * 16) * BK];
        gload16(pb0, Bd + 0);
        gload16(pb1, Bd + 8 * BK);
        pa0 += BK; pa1 += BK; pa2 += BK; pa3 += BK;
        pb0 += BK; pb1 += BK;
    };

    auto compute = [&](int buf) {
        const float* Asb = &As[buf][0];
        const float* Bsb = &Bs[buf][0];
        #pragma unroll
        for (int c = 0; c < 8; ++c) {
            const int ca = (c ^ kA) << 2;   // float offset within row
            const int cb = (c ^ kB) << 2;
            float4 b0 = *(const float4*)&Bsb[(tx * 4 + 0) * BK + cb];
            float4 b1 = *(const float4*)&Bsb[(tx * 4 + 1) * BK + cb];
            float4 b2 = *(const float4*)&Bsb[(tx * 4 + 2) * BK + cb];
            float4 b3 = *(const float4*)&Bsb[(tx * 4 + 3) * BK + cb];
            float4 a0 = *(const float4*)&Asb[(ty * 8 + 0) * BK + ca];
            float4 a1 = *(const float4*)&Asb[(ty * 8 + 1) * BK + ca];
            float4 a2 = *(const float4*)&Asb[(ty * 8 + 2) * BK + ca];
            float4 a3 = *(const float4*)&Asb[(ty * 8 + 3) * BK + ca];
            float4 a4 = *(const float4*)&Asb[(ty * 8 + 4) * BK + ca];
            float4 a5 = *(const float4*)&Asb[(ty * 8 + 5) * BK + ca];
            float4 a6 = *(const float4*)&Asb[(ty * 8 + 6) * BK + ca];
            float4 a7 = *(const float4*)&Asb[(ty * 8 + 7) * BK + ca];
#define ACC4(r, s, av, bv)                        \
            acc[r][s] += fabsf(av.x - bv.x);      \
            acc[r][s] += fabsf(av.y - bv.y);      \
            acc[r][s] += fabsf(av.z - bv.z);      \
            acc[r][s] += fabsf(av.w - bv.w);
#define ACCROW(r, av) ACC4(r,0,av,b0) ACC4(r,1,av,b1) ACC4(r,2,av,b2) ACC4(r,3,av,b3)
            ACCROW(0, a0) ACCROW(1, a1) ACCROW(2, a2) ACCROW(3, a3)
            ACCROW(4, a4) ACCROW(5, a5) ACCROW(6, a6) ACCROW(7, a7)
#undef ACCROW
#undef ACC4
        }
    };

    // 2-phase double-buffered k-loop
    stage(0);
    asm volatile("s_waitcnt vmcnt(0)" ::: "memory");
    __syncthreads();
    int buf = 0;
    for (int kt = 0; kt < D_DIM - BK; kt += BK) {
        stage(buf ^ 1);          // issue next tile's loads (in flight during compute)
        compute(buf);
        asm volatile("s_waitcnt vmcnt(0)" ::: "memory");
        __syncthreads();
        buf ^= 1;
    }
    compute(buf);

    // epilogue: x = (V[j] - c) * eps; per-row block max, then sum(exp(x - max))
    const float eps = 0.1f;
    float vj[TJ];
    #pragma unroll
    for (int s = 0; s < TJ; ++s) vj[s] = V[j0 + tx * TJ + s];

    #pragma unroll
    for (int r = 0; r < TI; ++r) {
        float x[TJ];
        #pragma unroll
        for (int s = 0; s < TJ; ++s) x[s] = (vj[s] - acc[r][s]) * eps;

        float m = fmaxf(fmaxf(x[0], x[1]), fmaxf(x[2], x[3]));
        m = fmaxf(m, __shfl_xor(m, 1));
        m = fmaxf(m, __shfl_xor(m, 2));
        m = fmaxf(m, __shfl_xor(m, 4));
        m = fmaxf(m, __shfl_xor(m, 8));

        float p = 0.0f;
        #pragma unroll
        for (int s = 0; s < TJ; ++s) p += expf(x[s] - m);
        p += __shfl_xor(p, 1);
        p += __shfl_xor(p, 2);
        p += __shfl_xor(p, 4);
        p += __shfl_xor(p, 8);

        if (tx == 0) {
            const int row = i0 + ty * TI + r;
            pmax [row * MB + jb] = m;
            psums[row * MB + jb] = p;
        }
    }
}

__global__ void ceps_row_logmean(const float* __restrict__ pmax,
                                 const float* __restrict__ psums,
                                 float* __restrict__ lrow,
                                 int N, int M)
{
    const int MB = M / BJ;
    int i = blockIdx.x * blockDim.x + threadIdx.x;
    if (i < N) {
        float m = -INFINITY;
        for (int jb = 0; jb < MB; ++jb) m = fmaxf(m, pmax[i * MB + jb]);
        float s = 0.0f;
        for (int jb = 0; jb < MB; ++jb)
            s += psums[i * MB + jb] * expf(pmax[i * MB + jb] - m);
        lrow[i] = m + logf(s) - logf((float)M);
    }
}

__global__ void ceps_final(const float* __restrict__ lrow,
                           const float* __restrict__ V,
                           float* __restrict__ out,
                           int N, int M)
{
    __shared__ float sl[256];
    __shared__ float sv[256];
    int t = threadIdx.x;
    float a = 0.0f, b = 0.0f;
    for (int i = t; i < N; i += 256) a += lrow[i];
    for (int i = t; i < M; i += 256) b += V[i];
    sl[t] = a; sv[t] = b;
    __syncthreads();
    for (int o = 128; o > 0; o >>= 1) {
        if (t < o) { sl[t] += sl[t + o]; sv[t] += sv[t + o]; }
        __syncthreads();
    }
    if (t == 0) {
        float fake_term = sv[0] / (float)M;
        float mean_log  = sl[0] / (float)N;
        out[0] = -fake_term + mean_log / 0.1f;
    }
}

extern "C" void kernel_launch(void* const* d_in, const int* in_sizes, int n_in,
                              void* d_out, int out_size, void* d_ws, size_t ws_size,
                              hipStream_t stream) {
    const float* A = (const float*)d_in[0];   // real_objects [N,1024]
    const float* B = (const float*)d_in[1];   // fake_objects [M,1024]
    const float* V = (const float*)d_in[2];   // fake_validity [M]

    const int N = in_sizes[0] / D_DIM;   // 2048
    const int M = in_sizes[1] / D_DIM;   // 2048
    const int MB = M / BJ;               // 32

    float* pmax  = (float*)d_ws;
    float* psums = pmax + (size_t)N * MB;
    float* lrow  = psums + (size_t)N * MB;

    dim3 grid(M / BJ, N / BI);           // (32, 16) = 512 blocks
    ceps_cdist_partial<<<grid, 256, 0, stream>>>(A, B, V, pmax, psums, N, M);
    ceps_row_logmean<<<(N + 255) / 256, 256, 0, stream>>>(pmax, psums, lrow, N, M);
    ceps_final<<<1, 256, 0, stream>>>(lrow, V, (float*)d_out, N, M);
}